// Round 4
// baseline (1108.590 us; speedup 1.0000x reference)
//
#include <hip/hip_runtime.h>

#define NLIT 8192
#define NCLS 16384
#define BATCH 4
#define DD 64
#define CCAP 64
#define LCAP 64
// node-major message buffers have one extra all-zero "dummy" row per batch
#define LSTRIDE (NLIT + 1)
#define CSTRIDE (NCLS + 1)

__device__ __forceinline__ float leaky(float x){ return x >= 0.f ? x : 0.01f*x; }

// ---- build sparse lists from dense A [NCLS, NLIT] ----
// exactly 8 strided uint4 loads per thread, issued before any test
__global__ __launch_bounds__(256) void extract_k(const uint4* __restrict__ A4,
    int* __restrict__ ccnt, int* __restrict__ clist,
    int* __restrict__ lcnt, int* __restrict__ llist){
  const int T = 16384*256;               // threads; total4 = 8*T
  int tid = blockIdx.x*256 + threadIdx.x;
  uint4 v[8];
  #pragma unroll
  for (int u=0;u<8;u++) v[u] = A4[tid + (size_t)u*T];
  #pragma unroll
  for (int u=0;u<8;u++){
    if (v[u].x | v[u].y | v[u].z | v[u].w){
      int i = tid + u*T;
      int c = i >> 11;                   // NLIT/4 = 2048 float4s per row
      int l = (i & 2047) << 2;
      unsigned vv[4] = {v[u].x, v[u].y, v[u].z, v[u].w};
      #pragma unroll
      for (int j=0;j<4;j++){
        if (vv[j]){
          int p = atomicAdd(&ccnt[c],1);
          if (p < CCAP) clist[c*CCAP+p] = l+j;
          int q = atomicAdd(&lcnt[l+j],1);
          if (q < LCAP) llist[(l+j)*LCAP+q] = c;
        }
      }
    }
  }
}

// ---- clamp counts, pad lists to multiple of 4 with dummy node, zero dummy rows ----
__global__ __launch_bounds__(256) void pad_k(int* __restrict__ ccnt, int* __restrict__ clist,
    int* __restrict__ lcnt, int* __restrict__ llist,
    float* __restrict__ LmsgT, float* __restrict__ CmsgT){
  int tid = blockIdx.x*256 + threadIdx.x;   // grid 96*256 = 24576
  if (tid < NCLS){
    int k = ccnt[tid]; if (k > CCAP) k = CCAP;
    ccnt[tid] = k;
    int e = (k+3) & ~3; if (e > CCAP) e = CCAP;
    for (int j=k;j<e;j++) clist[tid*CCAP+j] = NLIT;   // dummy literal
  } else {
    int l = tid - NCLS;
    int k = lcnt[l]; if (k > LCAP) k = LCAP;
    lcnt[l] = k;
    int e = (k+3) & ~3; if (e > LCAP) e = LCAP;
    for (int j=k;j<e;j++) llist[l*LCAP+j] = NCLS;     // dummy clause
  }
  if (tid < 256){
    int b = tid >> 6, f = tid & 63;
    LmsgT[((size_t)b*LSTRIDE + NLIT)*64 + f] = 0.f;
    CmsgT[((size_t)b*CSTRIDE + NCLS)*64 + f] = 0.f;
  }
}

// ---- Lmsg = W_Lmsg @ L_t + b, stored node-major [b, l, d] ----
__global__ __launch_bounds__(256) void lmsg_k(const float* __restrict__ L,
    const float* __restrict__ W, const float* __restrict__ bias, float* __restrict__ LmsgT){
  __shared__ float X[64][65];
  __shared__ float Y[64][65];
  int b  = blockIdx.x >> 7;
  int l0 = (blockIdx.x & 127) << 6;
  int lane = threadIdx.x & 63;
  int wg = __builtin_amdgcn_readfirstlane(threadIdx.x >> 6);
  const float* Lb = L + (size_t)b*DD*NLIT;
  #pragma unroll
  for (int r=0;r<16;r++){
    int i = wg + 4*r;
    X[lane][i] = Lb[(size_t)i*NLIT + l0 + lane];
  }
  __syncthreads();
  float acc[16];
  #pragma unroll
  for (int j=0;j<16;j++) acc[j] = bias[wg*16+j];
  #pragma unroll 4
  for (int i=0;i<64;i++){
    float x = X[lane][i];
    #pragma unroll
    for (int j=0;j<16;j++) acc[j] += W[(wg*16+j)*64+i] * x;
  }
  #pragma unroll
  for (int j=0;j<16;j++) Y[lane][wg*16+j] = acc[j];
  __syncthreads();
  float* out = LmsgT + ((size_t)b*LSTRIDE + l0)*64;
  #pragma unroll
  for (int r=0;r<16;r++){
    int cc = wg + 4*r;
    out[cc*64 + lane] = Y[cc][lane];
  }
}

// 4-edges-per-load gather: lane (g,h) loads float4 of edge j+g, features 4h..4h+3.
// list must be padded to multiple of 4 with dummy (zero-row) indices.
__device__ __forceinline__ void gather4(const float* __restrict__ src,
    const int* __restrict__ list, int k, int lane, float* __restrict__ sbrow){
  int g = lane >> 4;
  int h = lane & 15;
  float4 acc = {0.f,0.f,0.f,0.f};
  int rounds = (k + 3) >> 2;
  for (int r = 0; r < rounds; r++){
    int4 li = *(const int4*)&list[4*r];
    int idx = g==0 ? li.x : (g==1 ? li.y : (g==2 ? li.z : li.w));
    float4 v = *(const float4*)&src[(size_t)idx*64 + 4*h];
    acc.x += v.x; acc.y += v.y; acc.z += v.z; acc.w += v.w;
  }
  acc.x += __shfl_xor(acc.x, 16, 64); acc.y += __shfl_xor(acc.y, 16, 64);
  acc.z += __shfl_xor(acc.z, 16, 64); acc.w += __shfl_xor(acc.w, 16, 64);
  acc.x += __shfl_xor(acc.x, 32, 64); acc.y += __shfl_xor(acc.y, 32, 64);
  acc.z += __shfl_xor(acc.z, 32, 64); acc.w += __shfl_xor(acc.w, 32, 64);
  float val = g==0 ? acc.x : (g==1 ? acc.y : (g==2 ? acc.z : acc.w));
  sbrow[4*h + g] = val;
}

// ---- clause side: gather M_l, C_t_new = leaky(W_Cu@[C;M]+b), Cmsg = W_Cmsg@C_new+b ----
__global__ __launch_bounds__(256) void clause_k(const float* __restrict__ Ct,
    const float* __restrict__ LmsgT, const int* __restrict__ ccnt, const int* __restrict__ clist,
    const float* __restrict__ W_Cu, const float* __restrict__ b_Cu,
    const float* __restrict__ W_Cmsg, const float* __restrict__ b_Cmsg,
    float* __restrict__ CmsgT, float* __restrict__ outC){
  __shared__ float SA[64][65];
  __shared__ float SB[64][65];
  int b  = blockIdx.x >> 8;
  int c0 = (blockIdx.x & 255) << 6;
  int lane = threadIdx.x & 63;
  int wg = __builtin_amdgcn_readfirstlane(threadIdx.x >> 6);
  int kk[16];
  #pragma unroll
  for (int t=0;t<16;t++){
    int k = ccnt[c0 + wg*16 + t];
    kk[t] = k > CCAP ? CCAP : k;
  }
  const float* Cb = Ct + (size_t)b*DD*NCLS;
  #pragma unroll
  for (int r=0;r<16;r++){
    int i = wg + 4*r;
    SA[lane][i] = Cb[(size_t)i*NCLS + c0 + lane];
  }
  const float* Lm = LmsgT + (size_t)b*LSTRIDE*64;
  #pragma unroll 2
  for (int t=0;t<16;t++){
    int cc = wg*16 + t;
    gather4(Lm, &clist[(c0+cc)*CCAP], kk[t], lane, &SB[cc][0]);
  }
  __syncthreads();
  float v[16];
  {
    float acc[16];
    #pragma unroll
    for (int j=0;j<16;j++) acc[j] = b_Cu[wg*16+j];
    #pragma unroll 4
    for (int i=0;i<64;i++){
      float xa = SA[lane][i];
      float xm = SB[lane][i];
      #pragma unroll
      for (int j=0;j<16;j++){
        int o = wg*16+j;
        acc[j] += W_Cu[o*128+i]*xa + W_Cu[o*128+64+i]*xm;
      }
    }
    #pragma unroll
    for (int j=0;j<16;j++) v[j] = leaky(acc[j]);
  }
  float* oC = outC + (size_t)b*DD*NCLS;
  #pragma unroll
  for (int j=0;j<16;j++){
    int o = wg*16+j;
    oC[(size_t)o*NCLS + c0 + lane] = v[j];
  }
  __syncthreads();
  #pragma unroll
  for (int j=0;j<16;j++) SB[lane][wg*16+j] = v[j];
  __syncthreads();
  float acc2[16];
  #pragma unroll
  for (int j=0;j<16;j++) acc2[j] = b_Cmsg[wg*16+j];
  #pragma unroll 4
  for (int i=0;i<64;i++){
    float x = SB[lane][i];
    #pragma unroll
    for (int j=0;j<16;j++) acc2[j] += W_Cmsg[(wg*16+j)*64+i]*x;
  }
  #pragma unroll
  for (int j=0;j<16;j++) SA[lane][wg*16+j] = acc2[j];
  __syncthreads();
  float* oM = CmsgT + ((size_t)b*CSTRIDE + c0)*64;
  #pragma unroll
  for (int r=0;r<16;r++){
    int cc = wg + 4*r;
    oM[cc*64 + lane] = SA[cc][lane];
  }
}

// ---- literal side: gather M_c, L_t_new = leaky(W_Lu@[L;M;flip(L)]+b) ----
__global__ __launch_bounds__(256) void literal_k(const float* __restrict__ Lt,
    const float* __restrict__ CmsgT, const int* __restrict__ lcnt, const int* __restrict__ llist,
    const float* __restrict__ W_Lu, const float* __restrict__ b_Lu,
    float* __restrict__ outL){
  __shared__ float SX[64][65];
  __shared__ float SF[64][65];
  __shared__ float SM[64][65];
  int b  = blockIdx.x >> 7;
  int l0 = (blockIdx.x & 127) << 6;
  int lane = threadIdx.x & 63;
  int wg = __builtin_amdgcn_readfirstlane(threadIdx.x >> 6);
  int kk[16];
  #pragma unroll
  for (int t=0;t<16;t++){
    int k = lcnt[l0 + wg*16 + t];
    kk[t] = k > LCAP ? LCAP : k;
  }
  const float* Lb = Lt + (size_t)b*DD*NLIT;
  int f0 = l0 ^ 4096;   // (l + NLIT/2) % NLIT for a 64-aligned tile
  #pragma unroll
  for (int r=0;r<16;r++){
    int i = wg + 4*r;
    SX[lane][i] = Lb[(size_t)i*NLIT + l0 + lane];
    SF[lane][i] = Lb[(size_t)i*NLIT + f0 + lane];
  }
  const float* Cm = CmsgT + (size_t)b*CSTRIDE*64;
  #pragma unroll 2
  for (int t=0;t<16;t++){
    int cc = wg*16 + t;
    gather4(Cm, &llist[(l0+cc)*LCAP], kk[t], lane, &SM[cc][0]);
  }
  __syncthreads();
  float acc[16];
  #pragma unroll
  for (int j=0;j<16;j++) acc[j] = b_Lu[wg*16+j];
  #pragma unroll 4
  for (int i=0;i<64;i++){
    float xx = SX[lane][i], xm = SM[lane][i], xf = SF[lane][i];
    #pragma unroll
    for (int j=0;j<16;j++){
      int o = wg*16+j;
      acc[j] += W_Lu[o*192+i]*xx + W_Lu[o*192+64+i]*xm + W_Lu[o*192+128+i]*xf;
    }
  }
  float* oL = outL + (size_t)b*DD*NLIT;
  #pragma unroll
  for (int j=0;j<16;j++){
    int o = wg*16+j;
    oL[(size_t)o*NLIT + l0 + lane] = leaky(acc[j]);
  }
}

// ---- row sums of outL/outC ----
__global__ __launch_bounds__(256) void reduce_k(const float* __restrict__ outL,
    const float* __restrict__ outC, float* __restrict__ Lsum, float* __restrict__ Csum){
  __shared__ float red[4];
  int r = blockIdx.x;
  int t = threadIdx.x;
  float s = 0.f;
  if (r < 256){
    const float4* p = (const float4*)(outC + (size_t)r*NCLS);
    #pragma unroll
    for (int i=0;i<16;i++){
      float4 v = p[t + 256*i];
      s += v.x + v.y + v.z + v.w;
    }
  } else {
    const float4* p = (const float4*)(outL + (size_t)(r-256)*NLIT);
    #pragma unroll
    for (int i=0;i<8;i++){
      float4 v = p[t + 256*i];
      s += v.x + v.y + v.z + v.w;
    }
  }
  #pragma unroll
  for (int sft=32;sft>0;sft>>=1) s += __shfl_xor(s, sft, 64);
  if ((t & 63) == 0) red[t >> 6] = s;
  __syncthreads();
  if (t == 0){
    float tot = red[0] + red[1] + red[2] + red[3];
    if (r < 256) Csum[r] = tot; else Lsum[r-256] = tot;
  }
}

// ---- global update ----
__global__ void u_k(const float* __restrict__ Lsum, const float* __restrict__ Csum,
                    const float* __restrict__ Ut, const float* __restrict__ W,
                    const float* __restrict__ bias, float* __restrict__ outU){
  int t = threadIdx.x;
  int b = t >> 6, o = t & 63;
  float acc = bias[o];
  for (int i=0;i<64;i++){
    acc += W[o*192+i]*Lsum[b*64+i] + W[o*192+64+i]*Csum[b*64+i] + W[o*192+128+i]*Ut[b*64+i];
  }
  outU[t] = leaky(acc);
}

extern "C" void kernel_launch(void* const* d_in, const int* in_sizes, int n_in,
                              void* d_out, int out_size, void* d_ws, size_t ws_size,
                              hipStream_t stream){
  (void)in_sizes; (void)n_in; (void)out_size; (void)ws_size;
  const float* L_t    = (const float*)d_in[0];
  const float* C_t    = (const float*)d_in[1];
  const float* U_t    = (const float*)d_in[2];
  const float* A      = (const float*)d_in[3];
  // d_in[4] = A_t (unused)
  const float* W_Lmsg = (const float*)d_in[5];
  const float* b_Lmsg = (const float*)d_in[6];
  const float* W_Cmsg = (const float*)d_in[7];
  const float* b_Cmsg = (const float*)d_in[8];
  const float* W_Lu   = (const float*)d_in[9];
  const float* b_Lu   = (const float*)d_in[10];
  const float* W_Cu   = (const float*)d_in[11];
  const float* b_Cu   = (const float*)d_in[12];
  const float* W_Uu   = (const float*)d_in[13];
  const float* b_Uu   = (const float*)d_in[14];

  char* ws = (char*)d_ws;
  float* LmsgT = (float*)ws;                         // 4*8193*64*4  = 8,389,632
  float* CmsgT = (float*)(ws + 8389632);             // 4*16385*64*4 = 16,778,240
  int*   ccnt  = (int*)  (ws + 25167872);            // 64 KB
  int*   lcnt  = (int*)  (ws + 25233408);            // 32 KB
  float* Lsum  = (float*)(ws + 25266176);            // 1 KB
  float* Csum  = (float*)(ws + 25267200);            // 1 KB
  int*   clist = (int*)  (ws + 25268224);            // 4 MB
  int*   llist = (int*)  (ws + 29462528);            // 2 MB

  hipMemsetAsync(ws + 25167872, 0, 98304, stream);   // ccnt + lcnt

  float* outL = (float*)d_out;                       // [4,64,8192]
  float* outC = (float*)d_out + 2097152;             // [4,64,16384]
  float* outU = (float*)d_out + 6291456;             // [4,64,1]

  extract_k<<<16384, 256, 0, stream>>>((const uint4*)A, ccnt, clist, lcnt, llist);
  pad_k    <<<96,    256, 0, stream>>>(ccnt, clist, lcnt, llist, LmsgT, CmsgT);
  lmsg_k   <<<512,   256, 0, stream>>>(L_t, W_Lmsg, b_Lmsg, LmsgT);
  clause_k <<<1024,  256, 0, stream>>>(C_t, LmsgT, ccnt, clist, W_Cu, b_Cu,
                                       W_Cmsg, b_Cmsg, CmsgT, outC);
  literal_k<<<512,   256, 0, stream>>>(L_t, CmsgT, lcnt, llist, W_Lu, b_Lu, outL);
  reduce_k <<<512,   256, 0, stream>>>(outL, outC, Lsum, Csum);
  u_k      <<<1,     256, 0, stream>>>(Lsum, Csum, U_t, W_Uu, b_Uu, outU);
}

// Round 5
// 1089.266 us; speedup vs baseline: 1.0177x; 1.0177x over previous
//
#include <hip/hip_runtime.h>

#define NLIT 8192
#define NCLS 16384
#define DD 64
#define CCAP 64
#define LCAP 64

__device__ __forceinline__ float leaky(float x){ return x >= 0.f ? x : 0.01f*x; }

__device__ __forceinline__ int sel4(int g, int4 li){
  return g==0 ? li.x : (g==1 ? li.y : (g==2 ? li.z : li.w));
}

// ---- fused: extract sparse lists from A  +  Lmsg linear (independent work) ----
__global__ __launch_bounds__(256) void extract_lmsg_k(const uint4* __restrict__ A4,
    int* __restrict__ ccnt, int* __restrict__ clist,
    int* __restrict__ lcnt, int* __restrict__ llist,
    const float* __restrict__ L, const float* __restrict__ W,
    const float* __restrict__ bias, float* __restrict__ LmsgT){
  if (blockIdx.x < 16384){
    const int T = 16384*256;
    int tid = blockIdx.x*256 + threadIdx.x;
    uint4 v[8];
    #pragma unroll
    for (int u=0;u<8;u++) v[u] = A4[tid + (size_t)u*T];
    #pragma unroll
    for (int u=0;u<8;u++){
      if (v[u].x | v[u].y | v[u].z | v[u].w){
        int i = tid + u*T;
        int c = i >> 11;
        int l = (i & 2047) << 2;
        unsigned vv[4] = {v[u].x, v[u].y, v[u].z, v[u].w};
        #pragma unroll
        for (int j=0;j<4;j++){
          if (vv[j]){
            int p = atomicAdd(&ccnt[c],1);
            if (p < CCAP) clist[c*CCAP+p] = l+j;
            int q = atomicAdd(&lcnt[l+j],1);
            if (q < LCAP) llist[(l+j)*LCAP+q] = c;
          }
        }
      }
    }
  } else {
    __shared__ float X[64][65];
    __shared__ float Y[64][65];
    int bid = blockIdx.x - 16384;
    int b  = bid >> 7;
    int l0 = (bid & 127) << 6;
    int lane = threadIdx.x & 63;
    int wg = __builtin_amdgcn_readfirstlane(threadIdx.x >> 6);
    const float* Lb = L + (size_t)b*DD*NLIT;
    #pragma unroll
    for (int r=0;r<16;r++){
      int i = wg + 4*r;
      X[lane][i] = Lb[(size_t)i*NLIT + l0 + lane];
    }
    __syncthreads();
    float acc[16];
    #pragma unroll
    for (int j=0;j<16;j++) acc[j] = bias[wg*16+j];
    #pragma unroll 4
    for (int i=0;i<64;i++){
      float x = X[lane][i];
      #pragma unroll
      for (int j=0;j<16;j++) acc[j] += W[(wg*16+j)*64+i] * x;
    }
    #pragma unroll
    for (int j=0;j<16;j++) Y[lane][wg*16+j] = acc[j];
    __syncthreads();
    float* out = LmsgT + ((size_t)b*NLIT + l0)*64;
    #pragma unroll
    for (int r=0;r<16;r++){
      int cc = wg + 4*r;
      out[cc*64 + lane] = Y[cc][lane];
    }
  }
}

// grouped gather: 4 nodes' chains interleaved in one uniform-trip loop so
// 4 index loads + 4 row gathers are in flight per iteration. Predicated
// tails (no list padding needed). lane (g,h): edge-slot g, features 4h..4h+3.
__device__ __forceinline__ void gather_grp4(const float* __restrict__ src,
    const int* __restrict__ list, int cap, const int* kk, int lane,
    float (* __restrict__ sb)[65], int row0){
  int g = lane >> 4;
  int h = lane & 15;
  float4 a0={0.f,0.f,0.f,0.f}, a1=a0, a2=a0, a3=a0;
  int r0=(kk[0]+3)>>2, r1=(kk[1]+3)>>2, r2=(kk[2]+3)>>2, r3=(kk[3]+3)>>2;
  int Rm = max(max(r0,r1),max(r2,r3));
  for (int r=0;r<Rm;r++){
    if (r<r0){ int4 li=*(const int4*)&list[0*cap+4*r]; int e=4*r+g; bool vd=e<kk[0];
      int idx=vd?sel4(g,li):0; float4 x=*(const float4*)&src[(size_t)idx*64+4*h];
      if(vd){ a0.x+=x.x; a0.y+=x.y; a0.z+=x.z; a0.w+=x.w; } }
    if (r<r1){ int4 li=*(const int4*)&list[1*cap+4*r]; int e=4*r+g; bool vd=e<kk[1];
      int idx=vd?sel4(g,li):0; float4 x=*(const float4*)&src[(size_t)idx*64+4*h];
      if(vd){ a1.x+=x.x; a1.y+=x.y; a1.z+=x.z; a1.w+=x.w; } }
    if (r<r2){ int4 li=*(const int4*)&list[2*cap+4*r]; int e=4*r+g; bool vd=e<kk[2];
      int idx=vd?sel4(g,li):0; float4 x=*(const float4*)&src[(size_t)idx*64+4*h];
      if(vd){ a2.x+=x.x; a2.y+=x.y; a2.z+=x.z; a2.w+=x.w; } }
    if (r<r3){ int4 li=*(const int4*)&list[3*cap+4*r]; int e=4*r+g; bool vd=e<kk[3];
      int idx=vd?sel4(g,li):0; float4 x=*(const float4*)&src[(size_t)idx*64+4*h];
      if(vd){ a3.x+=x.x; a3.y+=x.y; a3.z+=x.z; a3.w+=x.w; } }
  }
  #pragma unroll
  for (int s=16;s<=32;s<<=1){
    a0.x+=__shfl_xor(a0.x,s,64); a0.y+=__shfl_xor(a0.y,s,64); a0.z+=__shfl_xor(a0.z,s,64); a0.w+=__shfl_xor(a0.w,s,64);
    a1.x+=__shfl_xor(a1.x,s,64); a1.y+=__shfl_xor(a1.y,s,64); a1.z+=__shfl_xor(a1.z,s,64); a1.w+=__shfl_xor(a1.w,s,64);
    a2.x+=__shfl_xor(a2.x,s,64); a2.y+=__shfl_xor(a2.y,s,64); a2.z+=__shfl_xor(a2.z,s,64); a2.w+=__shfl_xor(a2.w,s,64);
    a3.x+=__shfl_xor(a3.x,s,64); a3.y+=__shfl_xor(a3.y,s,64); a3.z+=__shfl_xor(a3.z,s,64); a3.w+=__shfl_xor(a3.w,s,64);
  }
  sb[row0+0][4*h+g] = g==0?a0.x:(g==1?a0.y:(g==2?a0.z:a0.w));
  sb[row0+1][4*h+g] = g==0?a1.x:(g==1?a1.y:(g==2?a1.z:a1.w));
  sb[row0+2][4*h+g] = g==0?a2.x:(g==1?a2.y:(g==2?a2.z:a2.w));
  sb[row0+3][4*h+g] = g==0?a3.x:(g==1?a3.y:(g==2?a3.z:a3.w));
}

// ---- clause side ----
__global__ __launch_bounds__(256) void clause_k(const float* __restrict__ Ct,
    const float* __restrict__ LmsgT, const int* __restrict__ ccnt, const int* __restrict__ clist,
    const float* __restrict__ W_Cu, const float* __restrict__ b_Cu,
    const float* __restrict__ W_Cmsg, const float* __restrict__ b_Cmsg,
    float* __restrict__ CmsgT, float* __restrict__ outC){
  __shared__ float SA[64][65];
  __shared__ float SB[64][65];
  int b  = blockIdx.x >> 8;
  int c0 = (blockIdx.x & 255) << 6;
  int lane = threadIdx.x & 63;
  int wg = __builtin_amdgcn_readfirstlane(threadIdx.x >> 6);
  int kk[16];
  #pragma unroll
  for (int t=0;t<16;t++){
    int k = ccnt[c0 + wg*16 + t];
    kk[t] = k > CCAP ? CCAP : k;
  }
  const float* Cb = Ct + (size_t)b*DD*NCLS;
  #pragma unroll
  for (int r=0;r<16;r++){
    int i = wg + 4*r;
    SA[lane][i] = Cb[(size_t)i*NCLS + c0 + lane];
  }
  const float* Lm = LmsgT + (size_t)b*NLIT*64;
  #pragma unroll
  for (int tg=0;tg<4;tg++){
    int row0 = wg*16 + tg*4;
    gather_grp4(Lm, &clist[(c0+row0)*CCAP], CCAP, &kk[tg*4], lane, SB, row0);
  }
  __syncthreads();
  float v[16];
  {
    float acc[16];
    #pragma unroll
    for (int j=0;j<16;j++) acc[j] = b_Cu[wg*16+j];
    #pragma unroll 4
    for (int i=0;i<64;i++){
      float xa = SA[lane][i];
      float xm = SB[lane][i];
      #pragma unroll
      for (int j=0;j<16;j++){
        int o = wg*16+j;
        acc[j] += W_Cu[o*128+i]*xa + W_Cu[o*128+64+i]*xm;
      }
    }
    #pragma unroll
    for (int j=0;j<16;j++) v[j] = leaky(acc[j]);
  }
  float* oC = outC + (size_t)b*DD*NCLS;
  #pragma unroll
  for (int j=0;j<16;j++){
    int o = wg*16+j;
    oC[(size_t)o*NCLS + c0 + lane] = v[j];
  }
  __syncthreads();
  #pragma unroll
  for (int j=0;j<16;j++) SB[lane][wg*16+j] = v[j];
  __syncthreads();
  float acc2[16];
  #pragma unroll
  for (int j=0;j<16;j++) acc2[j] = b_Cmsg[wg*16+j];
  #pragma unroll 4
  for (int i=0;i<64;i++){
    float x = SB[lane][i];
    #pragma unroll
    for (int j=0;j<16;j++) acc2[j] += W_Cmsg[(wg*16+j)*64+i]*x;
  }
  #pragma unroll
  for (int j=0;j<16;j++) SA[lane][wg*16+j] = acc2[j];
  __syncthreads();
  float* oM = CmsgT + ((size_t)b*NCLS + c0)*64;
  #pragma unroll
  for (int r=0;r<16;r++){
    int cc = wg + 4*r;
    oM[cc*64 + lane] = SA[cc][lane];
  }
}

// ---- fused: literal side (blocks 0..511)  +  outC row sums (blocks 512..767) ----
__global__ __launch_bounds__(256) void literal_redc_k(const float* __restrict__ Lt,
    const float* __restrict__ CmsgT, const int* __restrict__ lcnt, const int* __restrict__ llist,
    const float* __restrict__ W_Lu, const float* __restrict__ b_Lu,
    float* __restrict__ outL, const float* __restrict__ outC, float* __restrict__ Csum){
  if (blockIdx.x >= 512){
    __shared__ float red[4];
    int r = blockIdx.x - 512;
    int t = threadIdx.x;
    float s = 0.f;
    const float4* p = (const float4*)(outC + (size_t)r*NCLS);
    #pragma unroll
    for (int i=0;i<16;i++){
      float4 v = p[t + 256*i];
      s += v.x + v.y + v.z + v.w;
    }
    #pragma unroll
    for (int sft=32;sft>0;sft>>=1) s += __shfl_xor(s, sft, 64);
    if ((t & 63) == 0) red[t >> 6] = s;
    __syncthreads();
    if (t == 0) Csum[r] = red[0] + red[1] + red[2] + red[3];
    return;
  }
  __shared__ float SX[64][65];
  __shared__ float SF[64][65];
  __shared__ float SM[64][65];
  int b  = blockIdx.x >> 7;
  int l0 = (blockIdx.x & 127) << 6;
  int lane = threadIdx.x & 63;
  int wg = __builtin_amdgcn_readfirstlane(threadIdx.x >> 6);
  int kk[16];
  #pragma unroll
  for (int t=0;t<16;t++){
    int k = lcnt[l0 + wg*16 + t];
    kk[t] = k > LCAP ? LCAP : k;
  }
  const float* Lb = Lt + (size_t)b*DD*NLIT;
  int f0 = l0 ^ 4096;
  #pragma unroll
  for (int r=0;r<16;r++){
    int i = wg + 4*r;
    SX[lane][i] = Lb[(size_t)i*NLIT + l0 + lane];
    SF[lane][i] = Lb[(size_t)i*NLIT + f0 + lane];
  }
  const float* Cm = CmsgT + (size_t)b*NCLS*64;
  #pragma unroll
  for (int tg=0;tg<4;tg++){
    int row0 = wg*16 + tg*4;
    gather_grp4(Cm, &llist[(l0+row0)*LCAP], LCAP, &kk[tg*4], lane, SM, row0);
  }
  __syncthreads();
  float acc[16];
  #pragma unroll
  for (int j=0;j<16;j++) acc[j] = b_Lu[wg*16+j];
  #pragma unroll 4
  for (int i=0;i<64;i++){
    float xx = SX[lane][i], xm = SM[lane][i], xf = SF[lane][i];
    #pragma unroll
    for (int j=0;j<16;j++){
      int o = wg*16+j;
      acc[j] += W_Lu[o*192+i]*xx + W_Lu[o*192+64+i]*xm + W_Lu[o*192+128+i]*xf;
    }
  }
  float* oL = outL + (size_t)b*DD*NLIT;
  #pragma unroll
  for (int j=0;j<16;j++){
    int o = wg*16+j;
    oL[(size_t)o*NLIT + l0 + lane] = leaky(acc[j]);
  }
}

// ---- outL row sums ----
__global__ __launch_bounds__(256) void redl_k(const float* __restrict__ outL,
    float* __restrict__ Lsum){
  __shared__ float red[4];
  int r = blockIdx.x;
  int t = threadIdx.x;
  float s = 0.f;
  const float4* p = (const float4*)(outL + (size_t)r*NLIT);
  #pragma unroll
  for (int i=0;i<8;i++){
    float4 v = p[t + 256*i];
    s += v.x + v.y + v.z + v.w;
  }
  #pragma unroll
  for (int sft=32;sft>0;sft>>=1) s += __shfl_xor(s, sft, 64);
  if ((t & 63) == 0) red[t >> 6] = s;
  __syncthreads();
  if (t == 0) Lsum[r] = red[0] + red[1] + red[2] + red[3];
}

// ---- global update ----
__global__ void u_k(const float* __restrict__ Lsum, const float* __restrict__ Csum,
                    const float* __restrict__ Ut, const float* __restrict__ W,
                    const float* __restrict__ bias, float* __restrict__ outU){
  int t = threadIdx.x;
  int b = t >> 6, o = t & 63;
  float acc = bias[o];
  for (int i=0;i<64;i++){
    acc += W[o*192+i]*Lsum[b*64+i] + W[o*192+64+i]*Csum[b*64+i] + W[o*192+128+i]*Ut[b*64+i];
  }
  outU[t] = leaky(acc);
}

extern "C" void kernel_launch(void* const* d_in, const int* in_sizes, int n_in,
                              void* d_out, int out_size, void* d_ws, size_t ws_size,
                              hipStream_t stream){
  (void)in_sizes; (void)n_in; (void)out_size; (void)ws_size;
  const float* L_t    = (const float*)d_in[0];
  const float* C_t    = (const float*)d_in[1];
  const float* U_t    = (const float*)d_in[2];
  const float* A      = (const float*)d_in[3];
  const float* W_Lmsg = (const float*)d_in[5];
  const float* b_Lmsg = (const float*)d_in[6];
  const float* W_Cmsg = (const float*)d_in[7];
  const float* b_Cmsg = (const float*)d_in[8];
  const float* W_Lu   = (const float*)d_in[9];
  const float* b_Lu   = (const float*)d_in[10];
  const float* W_Cu   = (const float*)d_in[11];
  const float* b_Cu   = (const float*)d_in[12];
  const float* W_Uu   = (const float*)d_in[13];
  const float* b_Uu   = (const float*)d_in[14];

  char* ws = (char*)d_ws;
  float* LmsgT = (float*)ws;                         // 8 MB
  float* CmsgT = (float*)(ws + 8388608);             // 16 MB
  int*   ccnt  = (int*)  (ws + 25165824);            // 64 KB
  int*   lcnt  = (int*)  (ws + 25231360);            // 32 KB
  float* Lsum  = (float*)(ws + 25264128);
  float* Csum  = (float*)(ws + 25265152);
  int*   clist = (int*)  (ws + 25266176);            // 4 MB
  int*   llist = (int*)  (ws + 29460480);            // 2 MB

  hipMemsetAsync(ws + 25165824, 0, 98304, stream);   // ccnt + lcnt

  float* outL = (float*)d_out;                       // [4,64,8192]
  float* outC = (float*)d_out + 2097152;             // [4,64,16384]
  float* outU = (float*)d_out + 6291456;             // [4,64,1]

  extract_lmsg_k<<<16896, 256, 0, stream>>>((const uint4*)A, ccnt, clist, lcnt, llist,
                                            L_t, W_Lmsg, b_Lmsg, LmsgT);
  clause_k      <<<1024,  256, 0, stream>>>(C_t, LmsgT, ccnt, clist, W_Cu, b_Cu,
                                            W_Cmsg, b_Cmsg, CmsgT, outC);
  literal_redc_k<<<768,   256, 0, stream>>>(L_t, CmsgT, lcnt, llist, W_Lu, b_Lu,
                                            outL, outC, Csum);
  redl_k        <<<256,   256, 0, stream>>>(outL, Lsum);
  u_k           <<<1,     256, 0, stream>>>(Lsum, Csum, U_t, W_Uu, b_Uu, outU);
}

// Round 6
// 1082.133 us; speedup vs baseline: 1.0244x; 1.0066x over previous
//
#include <hip/hip_runtime.h>

#define NLIT 8192
#define NCLS 16384
#define DD 64
#define CCAP 64
#define LCAP 64

__device__ __forceinline__ float leaky(float x){ return x >= 0.f ? x : 0.01f*x; }

__device__ __forceinline__ int sel4(int g, int4 li){
  return g==0 ? li.x : (g==1 ? li.y : (g==2 ? li.z : li.w));
}

// ---- fused: extract sparse lists from A  +  Lmsg linear (independent work) ----
__global__ __launch_bounds__(256) void extract_lmsg_k(const uint4* __restrict__ A4,
    int* __restrict__ ccnt, int* __restrict__ clist,
    int* __restrict__ lcnt, int* __restrict__ llist,
    const float* __restrict__ L, const float* __restrict__ W,
    const float* __restrict__ bias, float* __restrict__ LmsgT){
  if (blockIdx.x < 16384){
    const int T = 16384*256;
    int tid = blockIdx.x*256 + threadIdx.x;
    uint4 v[8];
    #pragma unroll
    for (int u=0;u<8;u++) v[u] = A4[tid + (size_t)u*T];
    #pragma unroll
    for (int u=0;u<8;u++){
      if (v[u].x | v[u].y | v[u].z | v[u].w){
        int i = tid + u*T;
        int c = i >> 11;
        int l = (i & 2047) << 2;
        unsigned vv[4] = {v[u].x, v[u].y, v[u].z, v[u].w};
        #pragma unroll
        for (int j=0;j<4;j++){
          if (vv[j]){
            int p = atomicAdd(&ccnt[c],1);
            if (p < CCAP) clist[c*CCAP+p] = l+j;
            int q = atomicAdd(&lcnt[l+j],1);
            if (q < LCAP) llist[(l+j)*LCAP+q] = c;
          }
        }
      }
    }
  } else {
    __shared__ float X[64][65];
    __shared__ float Y[64][65];
    int bid = blockIdx.x - 16384;
    int b  = bid >> 7;
    int l0 = (bid & 127) << 6;
    int lane = threadIdx.x & 63;
    int wg = __builtin_amdgcn_readfirstlane(threadIdx.x >> 6);
    const float* Lb = L + (size_t)b*DD*NLIT;
    #pragma unroll
    for (int r=0;r<16;r++){
      int i = wg + 4*r;
      X[lane][i] = Lb[(size_t)i*NLIT + l0 + lane];
    }
    __syncthreads();
    float acc[16];
    #pragma unroll
    for (int j=0;j<16;j++) acc[j] = bias[wg*16+j];
    #pragma unroll 4
    for (int i=0;i<64;i++){
      float x = X[lane][i];
      #pragma unroll
      for (int j=0;j<16;j++) acc[j] += W[(wg*16+j)*64+i] * x;
    }
    #pragma unroll
    for (int j=0;j<16;j++) Y[lane][wg*16+j] = acc[j];
    __syncthreads();
    float* out = LmsgT + ((size_t)b*NLIT + l0)*64;
    #pragma unroll
    for (int r=0;r<16;r++){
      int cc = wg + 4*r;
      out[cc*64 + lane] = Y[cc][lane];
    }
  }
}

// grouped gather: 4 nodes' chains interleaved in one uniform-trip loop so
// 4 index loads + 4 row gathers are in flight per iteration.
__device__ __forceinline__ void gather_grp4(const float* __restrict__ src,
    const int* __restrict__ list, int cap, const int* kk, int lane,
    float (* __restrict__ sb)[65], int row0){
  int g = lane >> 4;
  int h = lane & 15;
  float4 a0={0.f,0.f,0.f,0.f}, a1=a0, a2=a0, a3=a0;
  int r0=(kk[0]+3)>>2, r1=(kk[1]+3)>>2, r2=(kk[2]+3)>>2, r3=(kk[3]+3)>>2;
  int Rm = max(max(r0,r1),max(r2,r3));
  for (int r=0;r<Rm;r++){
    if (r<r0){ int4 li=*(const int4*)&list[0*cap+4*r]; int e=4*r+g; bool vd=e<kk[0];
      int idx=vd?sel4(g,li):0; float4 x=*(const float4*)&src[(size_t)idx*64+4*h];
      if(vd){ a0.x+=x.x; a0.y+=x.y; a0.z+=x.z; a0.w+=x.w; } }
    if (r<r1){ int4 li=*(const int4*)&list[1*cap+4*r]; int e=4*r+g; bool vd=e<kk[1];
      int idx=vd?sel4(g,li):0; float4 x=*(const float4*)&src[(size_t)idx*64+4*h];
      if(vd){ a1.x+=x.x; a1.y+=x.y; a1.z+=x.z; a1.w+=x.w; } }
    if (r<r2){ int4 li=*(const int4*)&list[2*cap+4*r]; int e=4*r+g; bool vd=e<kk[2];
      int idx=vd?sel4(g,li):0; float4 x=*(const float4*)&src[(size_t)idx*64+4*h];
      if(vd){ a2.x+=x.x; a2.y+=x.y; a2.z+=x.z; a2.w+=x.w; } }
    if (r<r3){ int4 li=*(const int4*)&list[3*cap+4*r]; int e=4*r+g; bool vd=e<kk[3];
      int idx=vd?sel4(g,li):0; float4 x=*(const float4*)&src[(size_t)idx*64+4*h];
      if(vd){ a3.x+=x.x; a3.y+=x.y; a3.z+=x.z; a3.w+=x.w; } }
  }
  #pragma unroll
  for (int s=16;s<=32;s<<=1){
    a0.x+=__shfl_xor(a0.x,s,64); a0.y+=__shfl_xor(a0.y,s,64); a0.z+=__shfl_xor(a0.z,s,64); a0.w+=__shfl_xor(a0.w,s,64);
    a1.x+=__shfl_xor(a1.x,s,64); a1.y+=__shfl_xor(a1.y,s,64); a1.z+=__shfl_xor(a1.z,s,64); a1.w+=__shfl_xor(a1.w,s,64);
    a2.x+=__shfl_xor(a2.x,s,64); a2.y+=__shfl_xor(a2.y,s,64); a2.z+=__shfl_xor(a2.z,s,64); a2.w+=__shfl_xor(a2.w,s,64);
    a3.x+=__shfl_xor(a3.x,s,64); a3.y+=__shfl_xor(a3.y,s,64); a3.z+=__shfl_xor(a3.z,s,64); a3.w+=__shfl_xor(a3.w,s,64);
  }
  sb[row0+0][4*h+g] = g==0?a0.x:(g==1?a0.y:(g==2?a0.z:a0.w));
  sb[row0+1][4*h+g] = g==0?a1.x:(g==1?a1.y:(g==2?a1.z:a1.w));
  sb[row0+2][4*h+g] = g==0?a2.x:(g==1?a2.y:(g==2?a2.z:a2.w));
  sb[row0+3][4*h+g] = g==0?a3.x:(g==1?a3.y:(g==2?a3.z:a3.w));
}

// ---- clause side ----
// XCD-aware swizzle: batch b -> XCD pair {2b,2b+1} so each XCD's L2 caches
// only its own batch's LmsgT slice (2 MB) + list slices.
__global__ __launch_bounds__(256) void clause_k(const float* __restrict__ Ct,
    const float* __restrict__ LmsgT, const int* __restrict__ ccnt, const int* __restrict__ clist,
    const float* __restrict__ W_Cu, const float* __restrict__ b_Cu,
    const float* __restrict__ W_Cmsg, const float* __restrict__ b_Cmsg,
    float* __restrict__ CmsgT, float* __restrict__ outC){
  __shared__ float SA[64][65];
  __shared__ float SB[64][65];
  int bx = blockIdx.x;
  int b  = (bx & 7) >> 1;                         // XCD i%8 -> batch i/2
  int c0 = (((bx >> 3) << 1) | (bx & 1)) << 6;    // 256 tiles
  int lane = threadIdx.x & 63;
  int wg = __builtin_amdgcn_readfirstlane(threadIdx.x >> 6);
  int kk[16];
  #pragma unroll
  for (int t=0;t<16;t++){
    int k = ccnt[c0 + wg*16 + t];
    kk[t] = k > CCAP ? CCAP : k;
  }
  const float* Cb = Ct + (size_t)b*DD*NCLS;
  #pragma unroll
  for (int r=0;r<16;r++){
    int i = wg + 4*r;
    SA[lane][i] = Cb[(size_t)i*NCLS + c0 + lane];
  }
  const float* Lm = LmsgT + (size_t)b*NLIT*64;
  #pragma unroll
  for (int tg=0;tg<4;tg++){
    int row0 = wg*16 + tg*4;
    gather_grp4(Lm, &clist[(c0+row0)*CCAP], CCAP, &kk[tg*4], lane, SB, row0);
  }
  __syncthreads();
  float v[16];
  {
    float acc[16];
    #pragma unroll
    for (int j=0;j<16;j++) acc[j] = b_Cu[wg*16+j];
    #pragma unroll 4
    for (int i=0;i<64;i++){
      float xa = SA[lane][i];
      float xm = SB[lane][i];
      #pragma unroll
      for (int j=0;j<16;j++){
        int o = wg*16+j;
        acc[j] += W_Cu[o*128+i]*xa + W_Cu[o*128+64+i]*xm;
      }
    }
    #pragma unroll
    for (int j=0;j<16;j++) v[j] = leaky(acc[j]);
  }
  float* oC = outC + (size_t)b*DD*NCLS;
  #pragma unroll
  for (int j=0;j<16;j++){
    int o = wg*16+j;
    oC[(size_t)o*NCLS + c0 + lane] = v[j];
  }
  __syncthreads();
  #pragma unroll
  for (int j=0;j<16;j++) SB[lane][wg*16+j] = v[j];
  __syncthreads();
  float acc2[16];
  #pragma unroll
  for (int j=0;j<16;j++) acc2[j] = b_Cmsg[wg*16+j];
  #pragma unroll 4
  for (int i=0;i<64;i++){
    float x = SB[lane][i];
    #pragma unroll
    for (int j=0;j<16;j++) acc2[j] += W_Cmsg[(wg*16+j)*64+i]*x;
  }
  #pragma unroll
  for (int j=0;j<16;j++) SA[lane][wg*16+j] = acc2[j];
  __syncthreads();
  float* oM = CmsgT + ((size_t)b*NCLS + c0)*64;
  #pragma unroll
  for (int r=0;r<16;r++){
    int cc = wg + 4*r;
    oM[cc*64 + lane] = SA[cc][lane];
  }
}

// ---- fused: literal side (blocks 0..511, XCD-swizzled)  +  outC row sums ----
__global__ __launch_bounds__(256) void literal_redc_k(const float* __restrict__ Lt,
    const float* __restrict__ CmsgT, const int* __restrict__ lcnt, const int* __restrict__ llist,
    const float* __restrict__ W_Lu, const float* __restrict__ b_Lu,
    float* __restrict__ outL, const float* __restrict__ outC, float* __restrict__ Csum){
  if (blockIdx.x >= 512){
    __shared__ float red[4];
    int r = blockIdx.x - 512;
    int t = threadIdx.x;
    float s = 0.f;
    const float4* p = (const float4*)(outC + (size_t)r*NCLS);
    #pragma unroll
    for (int i=0;i<16;i++){
      float4 v = p[t + 256*i];
      s += v.x + v.y + v.z + v.w;
    }
    #pragma unroll
    for (int sft=32;sft>0;sft>>=1) s += __shfl_xor(s, sft, 64);
    if ((t & 63) == 0) red[t >> 6] = s;
    __syncthreads();
    if (t == 0) Csum[r] = red[0] + red[1] + red[2] + red[3];
    return;
  }
  __shared__ float SX[64][65];
  __shared__ float SF[64][65];
  __shared__ float SM[64][65];
  int bx = blockIdx.x;
  int b  = (bx & 7) >> 1;                         // XCD-aware: batch -> XCD pair
  int l0 = (((bx >> 3) << 1) | (bx & 1)) << 6;    // 128 tiles
  int lane = threadIdx.x & 63;
  int wg = __builtin_amdgcn_readfirstlane(threadIdx.x >> 6);
  int kk[16];
  #pragma unroll
  for (int t=0;t<16;t++){
    int k = lcnt[l0 + wg*16 + t];
    kk[t] = k > LCAP ? LCAP : k;
  }
  const float* Lb = Lt + (size_t)b*DD*NLIT;
  int f0 = l0 ^ 4096;
  #pragma unroll
  for (int r=0;r<16;r++){
    int i = wg + 4*r;
    SX[lane][i] = Lb[(size_t)i*NLIT + l0 + lane];
    SF[lane][i] = Lb[(size_t)i*NLIT + f0 + lane];
  }
  const float* Cm = CmsgT + (size_t)b*NCLS*64;
  #pragma unroll
  for (int tg=0;tg<4;tg++){
    int row0 = wg*16 + tg*4;
    gather_grp4(Cm, &llist[(l0+row0)*LCAP], LCAP, &kk[tg*4], lane, SM, row0);
  }
  __syncthreads();
  float acc[16];
  #pragma unroll
  for (int j=0;j<16;j++) acc[j] = b_Lu[wg*16+j];
  #pragma unroll 4
  for (int i=0;i<64;i++){
    float xx = SX[lane][i], xm = SM[lane][i], xf = SF[lane][i];
    #pragma unroll
    for (int j=0;j<16;j++){
      int o = wg*16+j;
      acc[j] += W_Lu[o*192+i]*xx + W_Lu[o*192+64+i]*xm + W_Lu[o*192+128+i]*xf;
    }
  }
  float* oL = outL + (size_t)b*DD*NLIT;
  #pragma unroll
  for (int j=0;j<16;j++){
    int o = wg*16+j;
    oL[(size_t)o*NLIT + l0 + lane] = leaky(acc[j]);
  }
}

// ---- outL row sums ----
__global__ __launch_bounds__(256) void redl_k(const float* __restrict__ outL,
    float* __restrict__ Lsum){
  __shared__ float red[4];
  int r = blockIdx.x;
  int t = threadIdx.x;
  float s = 0.f;
  const float4* p = (const float4*)(outL + (size_t)r*NLIT);
  #pragma unroll
  for (int i=0;i<8;i++){
    float4 v = p[t + 256*i];
    s += v.x + v.y + v.z + v.w;
  }
  #pragma unroll
  for (int sft=32;sft>0;sft>>=1) s += __shfl_xor(s, sft, 64);
  if ((t & 63) == 0) red[t >> 6] = s;
  __syncthreads();
  if (t == 0) Lsum[r] = red[0] + red[1] + red[2] + red[3];
}

// ---- global update ----
__global__ void u_k(const float* __restrict__ Lsum, const float* __restrict__ Csum,
                    const float* __restrict__ Ut, const float* __restrict__ W,
                    const float* __restrict__ bias, float* __restrict__ outU){
  int t = threadIdx.x;
  int b = t >> 6, o = t & 63;
  float acc = bias[o];
  for (int i=0;i<64;i++){
    acc += W[o*192+i]*Lsum[b*64+i] + W[o*192+64+i]*Csum[b*64+i] + W[o*192+128+i]*Ut[b*64+i];
  }
  outU[t] = leaky(acc);
}

extern "C" void kernel_launch(void* const* d_in, const int* in_sizes, int n_in,
                              void* d_out, int out_size, void* d_ws, size_t ws_size,
                              hipStream_t stream){
  (void)in_sizes; (void)n_in; (void)out_size; (void)ws_size;
  const float* L_t    = (const float*)d_in[0];
  const float* C_t    = (const float*)d_in[1];
  const float* U_t    = (const float*)d_in[2];
  const float* A      = (const float*)d_in[3];
  const float* W_Lmsg = (const float*)d_in[5];
  const float* b_Lmsg = (const float*)d_in[6];
  const float* W_Cmsg = (const float*)d_in[7];
  const float* b_Cmsg = (const float*)d_in[8];
  const float* W_Lu   = (const float*)d_in[9];
  const float* b_Lu   = (const float*)d_in[10];
  const float* W_Cu   = (const float*)d_in[11];
  const float* b_Cu   = (const float*)d_in[12];
  const float* W_Uu   = (const float*)d_in[13];
  const float* b_Uu   = (const float*)d_in[14];

  char* ws = (char*)d_ws;
  float* LmsgT = (float*)ws;                         // 8 MB
  float* CmsgT = (float*)(ws + 8388608);             // 16 MB
  int*   ccnt  = (int*)  (ws + 25165824);            // 64 KB
  int*   lcnt  = (int*)  (ws + 25231360);            // 32 KB
  float* Lsum  = (float*)(ws + 25264128);
  float* Csum  = (float*)(ws + 25265152);
  int*   clist = (int*)  (ws + 25266176);            // 4 MB
  int*   llist = (int*)  (ws + 29460480);            // 2 MB

  hipMemsetAsync(ws + 25165824, 0, 98304, stream);   // ccnt + lcnt

  float* outL = (float*)d_out;                       // [4,64,8192]
  float* outC = (float*)d_out + 2097152;             // [4,64,16384]
  float* outU = (float*)d_out + 6291456;             // [4,64,1]

  extract_lmsg_k<<<16896, 256, 0, stream>>>((const uint4*)A, ccnt, clist, lcnt, llist,
                                            L_t, W_Lmsg, b_Lmsg, LmsgT);
  clause_k      <<<1024,  256, 0, stream>>>(C_t, LmsgT, ccnt, clist, W_Cu, b_Cu,
                                            W_Cmsg, b_Cmsg, CmsgT, outC);
  literal_redc_k<<<768,   256, 0, stream>>>(L_t, CmsgT, lcnt, llist, W_Lu, b_Lu,
                                            outL, outC, Csum);
  redl_k        <<<256,   256, 0, stream>>>(outL, Lsum);
  u_k           <<<1,     256, 0, stream>>>(Lsum, Csum, U_t, W_Uu, b_Uu, outU);
}

// Round 7
// 1046.420 us; speedup vs baseline: 1.0594x; 1.0341x over previous
//
#include <hip/hip_runtime.h>

#define NLIT 8192
#define NCLS 16384
#define DD 64
#define CCAP 64
#define LCAP 64

__device__ __forceinline__ float leaky(float x){ return x >= 0.f ? x : 0.01f*x; }

__device__ __forceinline__ int sel4(int g, int4 li){
  return g==0 ? li.x : (g==1 ? li.y : (g==2 ? li.z : li.w));
}

// ---- fused: extract sparse lists from A  +  Lmsg linear (independent work) ----
__global__ __launch_bounds__(256) void extract_lmsg_k(const uint4* __restrict__ A4,
    int* __restrict__ ccnt, int* __restrict__ clist,
    int* __restrict__ lcnt, int* __restrict__ llist,
    const float* __restrict__ L, const float* __restrict__ W,
    const float* __restrict__ bias, float* __restrict__ LmsgT){
  if (blockIdx.x < 16384){
    const int T = 16384*256;
    int tid = blockIdx.x*256 + threadIdx.x;
    uint4 v[8];
    #pragma unroll
    for (int u=0;u<8;u++) v[u] = A4[tid + (size_t)u*T];
    #pragma unroll
    for (int u=0;u<8;u++){
      if (v[u].x | v[u].y | v[u].z | v[u].w){
        int i = tid + u*T;
        int c = i >> 11;
        int l = (i & 2047) << 2;
        unsigned vv[4] = {v[u].x, v[u].y, v[u].z, v[u].w};
        #pragma unroll
        for (int j=0;j<4;j++){
          if (vv[j]){
            int p = atomicAdd(&ccnt[c],1);
            if (p < CCAP) clist[c*CCAP+p] = l+j;
            int q = atomicAdd(&lcnt[l+j],1);
            if (q < LCAP) llist[(l+j)*LCAP+q] = c;
          }
        }
      }
    }
  } else {
    __shared__ float X[64][65];
    __shared__ float Y[64][65];
    int bid = blockIdx.x - 16384;                     // 0..511; XCD = bid%8
    int b   = (bid & 7) >> 1;                         // writer batch->XCD pair,
    int l0  = (((bid >> 3) << 1) | (bid & 1)) << 6;   // matches clause reader swizzle
    int lane = threadIdx.x & 63;
    int wg = __builtin_amdgcn_readfirstlane(threadIdx.x >> 6);
    const float* Lb = L + (size_t)b*DD*NLIT;
    #pragma unroll
    for (int r=0;r<16;r++){
      int i = wg + 4*r;
      X[lane][i] = Lb[(size_t)i*NLIT + l0 + lane];
    }
    __syncthreads();
    float acc[16];
    #pragma unroll
    for (int j=0;j<16;j++) acc[j] = bias[wg*16+j];
    #pragma unroll 4
    for (int i=0;i<64;i++){
      float x = X[lane][i];
      #pragma unroll
      for (int j=0;j<16;j++) acc[j] += W[(wg*16+j)*64+i] * x;
    }
    #pragma unroll
    for (int j=0;j<16;j++) Y[lane][wg*16+j] = acc[j];
    __syncthreads();
    float* out = LmsgT + ((size_t)b*NLIT + l0)*64;
    #pragma unroll
    for (int r=0;r<16;r++){
      int cc = wg + 4*r;
      out[cc*64 + lane] = Y[cc][lane];
    }
  }
}

// grouped gather: 4 nodes' chains interleaved in one uniform-trip loop.
__device__ __forceinline__ void gather_grp4(const float* __restrict__ src,
    const int* __restrict__ list, int cap, const int* kk, int lane,
    float (* __restrict__ sb)[65], int row0){
  int g = lane >> 4;
  int h = lane & 15;
  float4 a0={0.f,0.f,0.f,0.f}, a1=a0, a2=a0, a3=a0;
  int r0=(kk[0]+3)>>2, r1=(kk[1]+3)>>2, r2=(kk[2]+3)>>2, r3=(kk[3]+3)>>2;
  int Rm = max(max(r0,r1),max(r2,r3));
  for (int r=0;r<Rm;r++){
    if (r<r0){ int4 li=*(const int4*)&list[0*cap+4*r]; int e=4*r+g; bool vd=e<kk[0];
      int idx=vd?sel4(g,li):0; float4 x=*(const float4*)&src[(size_t)idx*64+4*h];
      if(vd){ a0.x+=x.x; a0.y+=x.y; a0.z+=x.z; a0.w+=x.w; } }
    if (r<r1){ int4 li=*(const int4*)&list[1*cap+4*r]; int e=4*r+g; bool vd=e<kk[1];
      int idx=vd?sel4(g,li):0; float4 x=*(const float4*)&src[(size_t)idx*64+4*h];
      if(vd){ a1.x+=x.x; a1.y+=x.y; a1.z+=x.z; a1.w+=x.w; } }
    if (r<r2){ int4 li=*(const int4*)&list[2*cap+4*r]; int e=4*r+g; bool vd=e<kk[2];
      int idx=vd?sel4(g,li):0; float4 x=*(const float4*)&src[(size_t)idx*64+4*h];
      if(vd){ a2.x+=x.x; a2.y+=x.y; a2.z+=x.z; a2.w+=x.w; } }
    if (r<r3){ int4 li=*(const int4*)&list[3*cap+4*r]; int e=4*r+g; bool vd=e<kk[3];
      int idx=vd?sel4(g,li):0; float4 x=*(const float4*)&src[(size_t)idx*64+4*h];
      if(vd){ a3.x+=x.x; a3.y+=x.y; a3.z+=x.z; a3.w+=x.w; } }
  }
  #pragma unroll
  for (int s=16;s<=32;s<<=1){
    a0.x+=__shfl_xor(a0.x,s,64); a0.y+=__shfl_xor(a0.y,s,64); a0.z+=__shfl_xor(a0.z,s,64); a0.w+=__shfl_xor(a0.w,s,64);
    a1.x+=__shfl_xor(a1.x,s,64); a1.y+=__shfl_xor(a1.y,s,64); a1.z+=__shfl_xor(a1.z,s,64); a1.w+=__shfl_xor(a1.w,s,64);
    a2.x+=__shfl_xor(a2.x,s,64); a2.y+=__shfl_xor(a2.y,s,64); a2.z+=__shfl_xor(a2.z,s,64); a2.w+=__shfl_xor(a2.w,s,64);
    a3.x+=__shfl_xor(a3.x,s,64); a3.y+=__shfl_xor(a3.y,s,64); a3.z+=__shfl_xor(a3.z,s,64); a3.w+=__shfl_xor(a3.w,s,64);
  }
  sb[row0+0][4*h+g] = g==0?a0.x:(g==1?a0.y:(g==2?a0.z:a0.w));
  sb[row0+1][4*h+g] = g==0?a1.x:(g==1?a1.y:(g==2?a1.z:a1.w));
  sb[row0+2][4*h+g] = g==0?a2.x:(g==1?a2.y:(g==2?a2.z:a2.w));
  sb[row0+3][4*h+g] = g==0?a3.x:(g==1?a3.y:(g==2?a3.z:a3.w));
}

// ---- clause side: 512 threads (8 waves), 8 nodes/wave gather, 8 outputs/wave linear ----
__global__ __launch_bounds__(512) void clause_k(const float* __restrict__ Ct,
    const float* __restrict__ LmsgT, const int* __restrict__ ccnt, const int* __restrict__ clist,
    const float* __restrict__ W_Cu, const float* __restrict__ b_Cu,
    const float* __restrict__ W_Cmsg, const float* __restrict__ b_Cmsg,
    float* __restrict__ CmsgT, float* __restrict__ outC){
  __shared__ float SA[64][65];
  __shared__ float SB[64][65];
  int bx = blockIdx.x;
  int b  = (bx & 7) >> 1;                         // XCD pair -> batch
  int c0 = (((bx >> 3) << 1) | (bx & 1)) << 6;
  int lane = threadIdx.x & 63;
  int wg = __builtin_amdgcn_readfirstlane(threadIdx.x >> 6);   // 0..7
  int kk[8];
  #pragma unroll
  for (int t=0;t<8;t++){
    int k = ccnt[c0 + wg*8 + t];
    kk[t] = k > CCAP ? CCAP : k;
  }
  const float* Cb = Ct + (size_t)b*DD*NCLS;
  #pragma unroll
  for (int r=0;r<8;r++){
    int i = wg + 8*r;
    SA[lane][i] = Cb[(size_t)i*NCLS + c0 + lane];
  }
  const float* Lm = LmsgT + (size_t)b*NLIT*64;
  #pragma unroll
  for (int tg=0;tg<2;tg++){
    int row0 = wg*8 + tg*4;
    gather_grp4(Lm, &clist[(c0+row0)*CCAP], CCAP, &kk[tg*4], lane, SB, row0);
  }
  __syncthreads();
  float v[8];
  {
    float acc[8];
    #pragma unroll
    for (int j=0;j<8;j++) acc[j] = b_Cu[wg*8+j];
    #pragma unroll 4
    for (int i=0;i<64;i++){
      float xa = SA[lane][i];
      float xm = SB[lane][i];
      #pragma unroll
      for (int j=0;j<8;j++){
        int o = wg*8+j;
        acc[j] += W_Cu[o*128+i]*xa + W_Cu[o*128+64+i]*xm;
      }
    }
    #pragma unroll
    for (int j=0;j<8;j++) v[j] = leaky(acc[j]);
  }
  float* oC = outC + (size_t)b*DD*NCLS;
  #pragma unroll
  for (int j=0;j<8;j++){
    int o = wg*8+j;
    oC[(size_t)o*NCLS + c0 + lane] = v[j];
  }
  __syncthreads();
  #pragma unroll
  for (int j=0;j<8;j++) SB[lane][wg*8+j] = v[j];
  __syncthreads();
  float acc2[8];
  #pragma unroll
  for (int j=0;j<8;j++) acc2[j] = b_Cmsg[wg*8+j];
  #pragma unroll 4
  for (int i=0;i<64;i++){
    float x = SB[lane][i];
    #pragma unroll
    for (int j=0;j<8;j++) acc2[j] += W_Cmsg[(wg*8+j)*64+i]*x;
  }
  #pragma unroll
  for (int j=0;j<8;j++) SA[lane][wg*8+j] = acc2[j];
  __syncthreads();
  float* oM = CmsgT + ((size_t)b*NCLS + c0)*64;
  #pragma unroll
  for (int r=0;r<8;r++){
    int cc = wg + 8*r;
    oM[cc*64 + lane] = SA[cc][lane];
  }
}

// ---- fused: literal side (blocks 0..511, 512 thr)  +  outC row sums (512..767) ----
__global__ __launch_bounds__(512) void literal_redc_k(const float* __restrict__ Lt,
    const float* __restrict__ CmsgT, const int* __restrict__ lcnt, const int* __restrict__ llist,
    const float* __restrict__ W_Lu, const float* __restrict__ b_Lu,
    float* __restrict__ outL, const float* __restrict__ outC, float* __restrict__ Csum){
  if (blockIdx.x >= 512){
    __shared__ float red[8];
    int r = blockIdx.x - 512;
    int t = threadIdx.x;
    float s = 0.f;
    const float4* p = (const float4*)(outC + (size_t)r*NCLS);
    #pragma unroll
    for (int i=0;i<8;i++){
      float4 v = p[t + 512*i];
      s += v.x + v.y + v.z + v.w;
    }
    #pragma unroll
    for (int sft=32;sft>0;sft>>=1) s += __shfl_xor(s, sft, 64);
    if ((t & 63) == 0) red[t >> 6] = s;
    __syncthreads();
    if (t == 0){
      float tot = 0.f;
      #pragma unroll
      for (int i=0;i<8;i++) tot += red[i];
      Csum[r] = tot;
    }
    return;
  }
  __shared__ float SX[64][65];
  __shared__ float SF[64][65];
  __shared__ float SM[64][65];
  int bx = blockIdx.x;
  int b  = (bx & 7) >> 1;
  int l0 = (((bx >> 3) << 1) | (bx & 1)) << 6;
  int lane = threadIdx.x & 63;
  int wg = __builtin_amdgcn_readfirstlane(threadIdx.x >> 6);   // 0..7
  int kk[8];
  #pragma unroll
  for (int t=0;t<8;t++){
    int k = lcnt[l0 + wg*8 + t];
    kk[t] = k > LCAP ? LCAP : k;
  }
  const float* Lb = Lt + (size_t)b*DD*NLIT;
  int f0 = l0 ^ 4096;
  #pragma unroll
  for (int r=0;r<8;r++){
    int i = wg + 8*r;
    SX[lane][i] = Lb[(size_t)i*NLIT + l0 + lane];
    SF[lane][i] = Lb[(size_t)i*NLIT + f0 + lane];
  }
  const float* Cm = CmsgT + (size_t)b*NCLS*64;
  #pragma unroll
  for (int tg=0;tg<2;tg++){
    int row0 = wg*8 + tg*4;
    gather_grp4(Cm, &llist[(l0+row0)*LCAP], LCAP, &kk[tg*4], lane, SM, row0);
  }
  __syncthreads();
  float acc[8];
  #pragma unroll
  for (int j=0;j<8;j++) acc[j] = b_Lu[wg*8+j];
  #pragma unroll 4
  for (int i=0;i<64;i++){
    float xx = SX[lane][i], xm = SM[lane][i], xf = SF[lane][i];
    #pragma unroll
    for (int j=0;j<8;j++){
      int o = wg*8+j;
      acc[j] += W_Lu[o*192+i]*xx + W_Lu[o*192+64+i]*xm + W_Lu[o*192+128+i]*xf;
    }
  }
  float* oL = outL + (size_t)b*DD*NLIT;
  #pragma unroll
  for (int j=0;j<8;j++){
    int o = wg*8+j;
    oL[(size_t)o*NLIT + l0 + lane] = leaky(acc[j]);
  }
}

// ---- outL row sums ----
__global__ __launch_bounds__(256) void redl_k(const float* __restrict__ outL,
    float* __restrict__ Lsum){
  __shared__ float red[4];
  int r = blockIdx.x;
  int t = threadIdx.x;
  float s = 0.f;
  const float4* p = (const float4*)(outL + (size_t)r*NLIT);
  #pragma unroll
  for (int i=0;i<8;i++){
    float4 v = p[t + 256*i];
    s += v.x + v.y + v.z + v.w;
  }
  #pragma unroll
  for (int sft=32;sft>0;sft>>=1) s += __shfl_xor(s, sft, 64);
  if ((t & 63) == 0) red[t >> 6] = s;
  __syncthreads();
  if (t == 0) Lsum[r] = red[0] + red[1] + red[2] + red[3];
}

// ---- global update ----
__global__ void u_k(const float* __restrict__ Lsum, const float* __restrict__ Csum,
                    const float* __restrict__ Ut, const float* __restrict__ W,
                    const float* __restrict__ bias, float* __restrict__ outU){
  int t = threadIdx.x;
  int b = t >> 6, o = t & 63;
  float acc = bias[o];
  for (int i=0;i<64;i++){
    acc += W[o*192+i]*Lsum[b*64+i] + W[o*192+64+i]*Csum[b*64+i] + W[o*192+128+i]*Ut[b*64+i];
  }
  outU[t] = leaky(acc);
}

extern "C" void kernel_launch(void* const* d_in, const int* in_sizes, int n_in,
                              void* d_out, int out_size, void* d_ws, size_t ws_size,
                              hipStream_t stream){
  (void)in_sizes; (void)n_in; (void)out_size; (void)ws_size;
  const float* L_t    = (const float*)d_in[0];
  const float* C_t    = (const float*)d_in[1];
  const float* U_t    = (const float*)d_in[2];
  const float* A      = (const float*)d_in[3];
  const float* W_Lmsg = (const float*)d_in[5];
  const float* b_Lmsg = (const float*)d_in[6];
  const float* W_Cmsg = (const float*)d_in[7];
  const float* b_Cmsg = (const float*)d_in[8];
  const float* W_Lu   = (const float*)d_in[9];
  const float* b_Lu   = (const float*)d_in[10];
  const float* W_Cu   = (const float*)d_in[11];
  const float* b_Cu   = (const float*)d_in[12];
  const float* W_Uu   = (const float*)d_in[13];
  const float* b_Uu   = (const float*)d_in[14];

  char* ws = (char*)d_ws;
  float* LmsgT = (float*)ws;                         // 8 MB
  float* CmsgT = (float*)(ws + 8388608);             // 16 MB
  int*   ccnt  = (int*)  (ws + 25165824);            // 64 KB
  int*   lcnt  = (int*)  (ws + 25231360);            // 32 KB
  float* Lsum  = (float*)(ws + 25264128);
  float* Csum  = (float*)(ws + 25265152);
  int*   clist = (int*)  (ws + 25266176);            // 4 MB
  int*   llist = (int*)  (ws + 29460480);            // 2 MB

  hipMemsetAsync(ws + 25165824, 0, 98304, stream);   // ccnt + lcnt

  float* outL = (float*)d_out;                       // [4,64,8192]
  float* outC = (float*)d_out + 2097152;             // [4,64,16384]
  float* outU = (float*)d_out + 6291456;             // [4,64,1]

  extract_lmsg_k<<<16896, 256, 0, stream>>>((const uint4*)A, ccnt, clist, lcnt, llist,
                                            L_t, W_Lmsg, b_Lmsg, LmsgT);
  clause_k      <<<1024,  512, 0, stream>>>(C_t, LmsgT, ccnt, clist, W_Cu, b_Cu,
                                            W_Cmsg, b_Cmsg, CmsgT, outC);
  literal_redc_k<<<768,   512, 0, stream>>>(L_t, CmsgT, lcnt, llist, W_Lu, b_Lu,
                                            outL, outC, Csum);
  redl_k        <<<256,   256, 0, stream>>>(outL, Lsum);
  u_k           <<<1,     256, 0, stream>>>(Lsum, Csum, U_t, W_Uu, b_Uu, outU);
}

// Round 8
// 1043.940 us; speedup vs baseline: 1.0619x; 1.0024x over previous
//
#include <hip/hip_runtime.h>

#define NLIT 8192
#define NCLS 16384
#define DD 64
#define CCAP 64
#define LCAP 64

__device__ __forceinline__ float leaky(float x){ return x >= 0.f ? x : 0.01f*x; }

__device__ __forceinline__ int sel4(int g, int4 li){
  return g==0 ? li.x : (g==1 ? li.y : (g==2 ? li.z : li.w));
}

__device__ __forceinline__ float bf2f(unsigned short u){
  unsigned v = ((unsigned)u) << 16;
  union { unsigned u; float f; } c; c.u = v; return c.f;
}
__device__ __forceinline__ unsigned short f2bf(float f){
  union { float f; unsigned u; } c; c.f = f;
  unsigned b = c.u + 0x7fffu + ((c.u >> 16) & 1u);   // RNE
  return (unsigned short)(b >> 16);
}

// ---- fused: extract sparse lists from A  +  Lmsg linear (bf16 out) ----
__global__ __launch_bounds__(256) void extract_lmsg_k(const uint4* __restrict__ A4,
    int* __restrict__ ccnt, int* __restrict__ clist,
    int* __restrict__ lcnt, int* __restrict__ llist,
    const float* __restrict__ L, const float* __restrict__ W,
    const float* __restrict__ bias, unsigned short* __restrict__ LmsgT){
  if (blockIdx.x < 16384){
    const int T = 16384*256;
    int tid = blockIdx.x*256 + threadIdx.x;
    uint4 v[8];
    #pragma unroll
    for (int u=0;u<8;u++) v[u] = A4[tid + (size_t)u*T];
    #pragma unroll
    for (int u=0;u<8;u++){
      if (v[u].x | v[u].y | v[u].z | v[u].w){
        int i = tid + u*T;
        int c = i >> 11;
        int l = (i & 2047) << 2;
        unsigned vv[4] = {v[u].x, v[u].y, v[u].z, v[u].w};
        #pragma unroll
        for (int j=0;j<4;j++){
          if (vv[j]){
            int p = atomicAdd(&ccnt[c],1);
            if (p < CCAP) clist[c*CCAP+p] = l+j;
            int q = atomicAdd(&lcnt[l+j],1);
            if (q < LCAP) llist[(l+j)*LCAP+q] = c;
          }
        }
      }
    }
  } else {
    __shared__ float X[64][65];
    __shared__ float Y[64][65];
    int bid = blockIdx.x - 16384;                     // 0..511
    int b   = (bid & 7) >> 1;                         // writer batch->XCD pair
    int l0  = (((bid >> 3) << 1) | (bid & 1)) << 6;
    int lane = threadIdx.x & 63;
    int wg = __builtin_amdgcn_readfirstlane(threadIdx.x >> 6);
    const float* Lb = L + (size_t)b*DD*NLIT;
    #pragma unroll
    for (int r=0;r<16;r++){
      int i = wg + 4*r;
      X[lane][i] = Lb[(size_t)i*NLIT + l0 + lane];
    }
    __syncthreads();
    float acc[16];
    #pragma unroll
    for (int j=0;j<16;j++) acc[j] = bias[wg*16+j];
    #pragma unroll 4
    for (int i=0;i<64;i++){
      float x = X[lane][i];
      #pragma unroll
      for (int j=0;j<16;j++) acc[j] += W[(wg*16+j)*64+i] * x;
    }
    #pragma unroll
    for (int j=0;j<16;j++) Y[lane][wg*16+j] = acc[j];
    __syncthreads();
    unsigned short* out = LmsgT + ((size_t)b*NLIT + l0)*64;
    #pragma unroll
    for (int r=0;r<16;r++){
      int cc = wg + 4*r;
      out[cc*64 + lane] = f2bf(Y[cc][lane]);
    }
  }
}

// grouped gather (bf16 payload): 4 nodes interleaved, 4 edges/instr, 128 B/edge.
__device__ __forceinline__ void gather_grp4(const unsigned short* __restrict__ src,
    const int* __restrict__ list, int cap, const int* kk, int lane,
    float (* __restrict__ sb)[65], int row0){
  int g = lane >> 4;
  int h = lane & 15;
  float4 a0={0.f,0.f,0.f,0.f}, a1=a0, a2=a0, a3=a0;
  int r0=(kk[0]+3)>>2, r1=(kk[1]+3)>>2, r2=(kk[2]+3)>>2, r3=(kk[3]+3)>>2;
  int Rm = max(max(r0,r1),max(r2,r3));
  for (int r=0;r<Rm;r++){
    if (r<r0){ int4 li=*(const int4*)&list[0*cap+4*r]; int e=4*r+g; bool vd=e<kk[0];
      int idx=vd?sel4(g,li):0; ushort4 x=*(const ushort4*)&src[(size_t)idx*64+4*h];
      if(vd){ a0.x+=bf2f(x.x); a0.y+=bf2f(x.y); a0.z+=bf2f(x.z); a0.w+=bf2f(x.w); } }
    if (r<r1){ int4 li=*(const int4*)&list[1*cap+4*r]; int e=4*r+g; bool vd=e<kk[1];
      int idx=vd?sel4(g,li):0; ushort4 x=*(const ushort4*)&src[(size_t)idx*64+4*h];
      if(vd){ a1.x+=bf2f(x.x); a1.y+=bf2f(x.y); a1.z+=bf2f(x.z); a1.w+=bf2f(x.w); } }
    if (r<r2){ int4 li=*(const int4*)&list[2*cap+4*r]; int e=4*r+g; bool vd=e<kk[2];
      int idx=vd?sel4(g,li):0; ushort4 x=*(const ushort4*)&src[(size_t)idx*64+4*h];
      if(vd){ a2.x+=bf2f(x.x); a2.y+=bf2f(x.y); a2.z+=bf2f(x.z); a2.w+=bf2f(x.w); } }
    if (r<r3){ int4 li=*(const int4*)&list[3*cap+4*r]; int e=4*r+g; bool vd=e<kk[3];
      int idx=vd?sel4(g,li):0; ushort4 x=*(const ushort4*)&src[(size_t)idx*64+4*h];
      if(vd){ a3.x+=bf2f(x.x); a3.y+=bf2f(x.y); a3.z+=bf2f(x.z); a3.w+=bf2f(x.w); } }
  }
  #pragma unroll
  for (int s=16;s<=32;s<<=1){
    a0.x+=__shfl_xor(a0.x,s,64); a0.y+=__shfl_xor(a0.y,s,64); a0.z+=__shfl_xor(a0.z,s,64); a0.w+=__shfl_xor(a0.w,s,64);
    a1.x+=__shfl_xor(a1.x,s,64); a1.y+=__shfl_xor(a1.y,s,64); a1.z+=__shfl_xor(a1.z,s,64); a1.w+=__shfl_xor(a1.w,s,64);
    a2.x+=__shfl_xor(a2.x,s,64); a2.y+=__shfl_xor(a2.y,s,64); a2.z+=__shfl_xor(a2.z,s,64); a2.w+=__shfl_xor(a2.w,s,64);
    a3.x+=__shfl_xor(a3.x,s,64); a3.y+=__shfl_xor(a3.y,s,64); a3.z+=__shfl_xor(a3.z,s,64); a3.w+=__shfl_xor(a3.w,s,64);
  }
  sb[row0+0][4*h+g] = g==0?a0.x:(g==1?a0.y:(g==2?a0.z:a0.w));
  sb[row0+1][4*h+g] = g==0?a1.x:(g==1?a1.y:(g==2?a1.z:a1.w));
  sb[row0+2][4*h+g] = g==0?a2.x:(g==1?a2.y:(g==2?a2.z:a2.w));
  sb[row0+3][4*h+g] = g==0?a3.x:(g==1?a3.y:(g==2?a3.z:a3.w));
}

// ---- clause side: 512 threads, bf16 message in/out ----
__global__ __launch_bounds__(512) void clause_k(const float* __restrict__ Ct,
    const unsigned short* __restrict__ LmsgT, const int* __restrict__ ccnt, const int* __restrict__ clist,
    const float* __restrict__ W_Cu, const float* __restrict__ b_Cu,
    const float* __restrict__ W_Cmsg, const float* __restrict__ b_Cmsg,
    unsigned short* __restrict__ CmsgT, float* __restrict__ outC){
  __shared__ float SA[64][65];
  __shared__ float SB[64][65];
  int bx = blockIdx.x;
  int b  = (bx & 7) >> 1;
  int c0 = (((bx >> 3) << 1) | (bx & 1)) << 6;
  int lane = threadIdx.x & 63;
  int wg = __builtin_amdgcn_readfirstlane(threadIdx.x >> 6);   // 0..7
  int kk[8];
  #pragma unroll
  for (int t=0;t<8;t++){
    int k = ccnt[c0 + wg*8 + t];
    kk[t] = k > CCAP ? CCAP : k;
  }
  const float* Cb = Ct + (size_t)b*DD*NCLS;
  #pragma unroll
  for (int r=0;r<8;r++){
    int i = wg + 8*r;
    SA[lane][i] = Cb[(size_t)i*NCLS + c0 + lane];
  }
  const unsigned short* Lm = LmsgT + (size_t)b*NLIT*64;
  #pragma unroll
  for (int tg=0;tg<2;tg++){
    int row0 = wg*8 + tg*4;
    gather_grp4(Lm, &clist[(c0+row0)*CCAP], CCAP, &kk[tg*4], lane, SB, row0);
  }
  __syncthreads();
  float v[8];
  {
    float acc[8];
    #pragma unroll
    for (int j=0;j<8;j++) acc[j] = b_Cu[wg*8+j];
    #pragma unroll 4
    for (int i=0;i<64;i++){
      float xa = SA[lane][i];
      float xm = SB[lane][i];
      #pragma unroll
      for (int j=0;j<8;j++){
        int o = wg*8+j;
        acc[j] += W_Cu[o*128+i]*xa + W_Cu[o*128+64+i]*xm;
      }
    }
    #pragma unroll
    for (int j=0;j<8;j++) v[j] = leaky(acc[j]);
  }
  float* oC = outC + (size_t)b*DD*NCLS;
  #pragma unroll
  for (int j=0;j<8;j++){
    int o = wg*8+j;
    oC[(size_t)o*NCLS + c0 + lane] = v[j];
  }
  __syncthreads();
  #pragma unroll
  for (int j=0;j<8;j++) SB[lane][wg*8+j] = v[j];
  __syncthreads();
  float acc2[8];
  #pragma unroll
  for (int j=0;j<8;j++) acc2[j] = b_Cmsg[wg*8+j];
  #pragma unroll 4
  for (int i=0;i<64;i++){
    float x = SB[lane][i];
    #pragma unroll
    for (int j=0;j<8;j++) acc2[j] += W_Cmsg[(wg*8+j)*64+i]*x;
  }
  #pragma unroll
  for (int j=0;j<8;j++) SA[lane][wg*8+j] = acc2[j];
  __syncthreads();
  unsigned short* oM = CmsgT + ((size_t)b*NCLS + c0)*64;
  #pragma unroll
  for (int r=0;r<8;r++){
    int cc = wg + 8*r;
    oM[cc*64 + lane] = f2bf(SA[cc][lane]);
  }
}

// ---- fused: literal side (blocks 0..511)  +  outC row sums (512..767) ----
__global__ __launch_bounds__(512) void literal_redc_k(const float* __restrict__ Lt,
    const unsigned short* __restrict__ CmsgT, const int* __restrict__ lcnt, const int* __restrict__ llist,
    const float* __restrict__ W_Lu, const float* __restrict__ b_Lu,
    float* __restrict__ outL, const float* __restrict__ outC, float* __restrict__ Csum){
  if (blockIdx.x >= 512){
    __shared__ float red[8];
    int r = blockIdx.x - 512;
    int t = threadIdx.x;
    float s = 0.f;
    const float4* p = (const float4*)(outC + (size_t)r*NCLS);
    #pragma unroll
    for (int i=0;i<8;i++){
      float4 v = p[t + 512*i];
      s += v.x + v.y + v.z + v.w;
    }
    #pragma unroll
    for (int sft=32;sft>0;sft>>=1) s += __shfl_xor(s, sft, 64);
    if ((t & 63) == 0) red[t >> 6] = s;
    __syncthreads();
    if (t == 0){
      float tot = 0.f;
      #pragma unroll
      for (int i=0;i<8;i++) tot += red[i];
      Csum[r] = tot;
    }
    return;
  }
  __shared__ float SX[64][65];
  __shared__ float SF[64][65];
  __shared__ float SM[64][65];
  int bx = blockIdx.x;
  int b  = (bx & 7) >> 1;
  int l0 = (((bx >> 3) << 1) | (bx & 1)) << 6;
  int lane = threadIdx.x & 63;
  int wg = __builtin_amdgcn_readfirstlane(threadIdx.x >> 6);   // 0..7
  int kk[8];
  #pragma unroll
  for (int t=0;t<8;t++){
    int k = lcnt[l0 + wg*8 + t];
    kk[t] = k > LCAP ? LCAP : k;
  }
  const float* Lb = Lt + (size_t)b*DD*NLIT;
  int f0 = l0 ^ 4096;
  #pragma unroll
  for (int r=0;r<8;r++){
    int i = wg + 8*r;
    SX[lane][i] = Lb[(size_t)i*NLIT + l0 + lane];
    SF[lane][i] = Lb[(size_t)i*NLIT + f0 + lane];
  }
  const unsigned short* Cm = CmsgT + (size_t)b*NCLS*64;
  #pragma unroll
  for (int tg=0;tg<2;tg++){
    int row0 = wg*8 + tg*4;
    gather_grp4(Cm, &llist[(l0+row0)*LCAP], LCAP, &kk[tg*4], lane, SM, row0);
  }
  __syncthreads();
  float acc[8];
  #pragma unroll
  for (int j=0;j<8;j++) acc[j] = b_Lu[wg*8+j];
  #pragma unroll 4
  for (int i=0;i<64;i++){
    float xx = SX[lane][i], xm = SM[lane][i], xf = SF[lane][i];
    #pragma unroll
    for (int j=0;j<8;j++){
      int o = wg*8+j;
      acc[j] += W_Lu[o*192+i]*xx + W_Lu[o*192+64+i]*xm + W_Lu[o*192+128+i]*xf;
    }
  }
  float* oL = outL + (size_t)b*DD*NLIT;
  #pragma unroll
  for (int j=0;j<8;j++){
    int o = wg*8+j;
    oL[(size_t)o*NLIT + l0 + lane] = leaky(acc[j]);
  }
}

// ---- outL row sums ----
__global__ __launch_bounds__(256) void redl_k(const float* __restrict__ outL,
    float* __restrict__ Lsum){
  __shared__ float red[4];
  int r = blockIdx.x;
  int t = threadIdx.x;
  float s = 0.f;
  const float4* p = (const float4*)(outL + (size_t)r*NLIT);
  #pragma unroll
  for (int i=0;i<8;i++){
    float4 v = p[t + 256*i];
    s += v.x + v.y + v.z + v.w;
  }
  #pragma unroll
  for (int sft=32;sft>0;sft>>=1) s += __shfl_xor(s, sft, 64);
  if ((t & 63) == 0) red[t >> 6] = s;
  __syncthreads();
  if (t == 0) Lsum[r] = red[0] + red[1] + red[2] + red[3];
}

// ---- global update ----
__global__ void u_k(const float* __restrict__ Lsum, const float* __restrict__ Csum,
                    const float* __restrict__ Ut, const float* __restrict__ W,
                    const float* __restrict__ bias, float* __restrict__ outU){
  int t = threadIdx.x;
  int b = t >> 6, o = t & 63;
  float acc = bias[o];
  for (int i=0;i<64;i++){
    acc += W[o*192+i]*Lsum[b*64+i] + W[o*192+64+i]*Csum[b*64+i] + W[o*192+128+i]*Ut[b*64+i];
  }
  outU[t] = leaky(acc);
}

extern "C" void kernel_launch(void* const* d_in, const int* in_sizes, int n_in,
                              void* d_out, int out_size, void* d_ws, size_t ws_size,
                              hipStream_t stream){
  (void)in_sizes; (void)n_in; (void)out_size; (void)ws_size;
  const float* L_t    = (const float*)d_in[0];
  const float* C_t    = (const float*)d_in[1];
  const float* U_t    = (const float*)d_in[2];
  const float* A      = (const float*)d_in[3];
  const float* W_Lmsg = (const float*)d_in[5];
  const float* b_Lmsg = (const float*)d_in[6];
  const float* W_Cmsg = (const float*)d_in[7];
  const float* b_Cmsg = (const float*)d_in[8];
  const float* W_Lu   = (const float*)d_in[9];
  const float* b_Lu   = (const float*)d_in[10];
  const float* W_Cu   = (const float*)d_in[11];
  const float* b_Cu   = (const float*)d_in[12];
  const float* W_Uu   = (const float*)d_in[13];
  const float* b_Uu   = (const float*)d_in[14];

  char* ws = (char*)d_ws;
  unsigned short* LmsgT = (unsigned short*)ws;             // 4*8192*64*2  = 4 MB
  unsigned short* CmsgT = (unsigned short*)(ws + 4194304); // 4*16384*64*2 = 8 MB
  int*   ccnt  = (int*)  (ws + 12582912);                  // 64 KB
  int*   lcnt  = (int*)  (ws + 12648448);                  // 32 KB
  float* Lsum  = (float*)(ws + 12681216);
  float* Csum  = (float*)(ws + 12682240);
  int*   clist = (int*)  (ws + 12683264);                  // 4 MB
  int*   llist = (int*)  (ws + 16877568);                  // 2 MB

  hipMemsetAsync(ws + 12582912, 0, 98304, stream);         // ccnt + lcnt

  float* outL = (float*)d_out;                       // [4,64,8192]
  float* outC = (float*)d_out + 2097152;             // [4,64,16384]
  float* outU = (float*)d_out + 6291456;             // [4,64,1]

  extract_lmsg_k<<<16896, 256, 0, stream>>>((const uint4*)A, ccnt, clist, lcnt, llist,
                                            L_t, W_Lmsg, b_Lmsg, LmsgT);
  clause_k      <<<1024,  512, 0, stream>>>(C_t, LmsgT, ccnt, clist, W_Cu, b_Cu,
                                            W_Cmsg, b_Cmsg, CmsgT, outC);
  literal_redc_k<<<768,   512, 0, stream>>>(L_t, CmsgT, lcnt, llist, W_Lu, b_Lu,
                                            outL, outC, Csum);
  redl_k        <<<256,   256, 0, stream>>>(outL, Lsum);
  u_k           <<<1,     256, 0, stream>>>(Lsum, Csum, U_t, W_Uu, b_Uu, outU);
}